// Round 3
// baseline (357.444 us; speedup 1.0000x reference)
//
#include <hip/hip_runtime.h>
#include <hip/hip_bf16.h>
#include <math.h>
#include <stdint.h>

#define N_ROWS 8192
#define DIM 512
#define INV_TAU 5.0f
#define EXP5 148.41315910257660342f   // exp(1/tau) = exp(5)

typedef float f32x4 __attribute__((ext_vector_type(4)));
typedef int   i32x4 __attribute__((ext_vector_type(4)));
typedef int   i32x8 __attribute__((ext_vector_type(8)));

union Frag8 {
  i32x8 v8;
  struct { i32x4 lo, hi; } s;
};

__device__ __forceinline__ void gload_lds16(const void* g, void* l) {
  __builtin_amdgcn_global_load_lds(
      (__attribute__((address_space(1))) void*)(void*)g,
      (__attribute__((address_space(3))) void*)l,
      16, 0, 0);
}

// One block per row: L2 norms of z1,z2 row, fp32 diag dot, fp8(e4m3) h1,h2.
// Also zeroes the accumulator arrays and out (replaces memsets).
__global__ __launch_bounds__(256) void normalize_kernel(
    const float* __restrict__ z1, const float* __restrict__ z2,
    uint8_t* __restrict__ h1, uint8_t* __restrict__ h2,
    float* __restrict__ dvec,
    float* __restrict__ r1, float* __restrict__ r2,
    float* __restrict__ brow, float* __restrict__ bcol,
    float* __restrict__ out) {
  const int row = blockIdx.x;
  const int t = threadIdx.x;
  const float2 a = ((const float2*)(z1 + (size_t)row * DIM))[t];
  const float2 b = ((const float2*)(z2 + (size_t)row * DIM))[t];
  float s1 = a.x * a.x + a.y * a.y;
  float s2 = b.x * b.x + b.y * b.y;
  float s3 = a.x * b.x + a.y * b.y;
  for (int m = 32; m; m >>= 1) {
    s1 += __shfl_xor(s1, m);
    s2 += __shfl_xor(s2, m);
    s3 += __shfl_xor(s3, m);
  }
  __shared__ float red[3][4];
  const int wave = t >> 6;
  if ((t & 63) == 0) { red[0][wave] = s1; red[1][wave] = s2; red[2][wave] = s3; }
  __syncthreads();
  const float S1 = red[0][0] + red[0][1] + red[0][2] + red[0][3];
  const float S2 = red[1][0] + red[1][1] + red[1][2] + red[1][3];
  const float S3 = red[2][0] + red[2][1] + red[2][2] + red[2][3];
  const float inv1 = 1.0f / fmaxf(sqrtf(S1), 1e-12f);
  const float inv2 = 1.0f / fmaxf(sqrtf(S2), 1e-12f);
  // pack 2 adjacent fp8 per thread (cols 2t, 2t+1)
  const int pk1 = __builtin_amdgcn_cvt_pk_fp8_f32(a.x * inv1, a.y * inv1, 0, false);
  const int pk2 = __builtin_amdgcn_cvt_pk_fp8_f32(b.x * inv2, b.y * inv2, 0, false);
  ((uint16_t*)(h1 + (size_t)row * DIM))[t] = (uint16_t)pk1;
  ((uint16_t*)(h2 + (size_t)row * DIM))[t] = (uint16_t)pk2;
  if (t == 0) {
    dvec[row] = S3 * inv1 * inv2;
    r1[row] = 0.0f; r2[row] = 0.0f; brow[row] = 0.0f; bcol[row] = 0.0f;
    if (row == 0) out[0] = 0.0f;
  }
}

// grid (64,64,3):
//   z=0 -> exp(h1 h1^T) (symmetric: only j0>=i0 run; off-diag feed rows+cols)
//   z=1 -> same for h2 into r2
//   z=2 -> exp(h1 h2^T) full grid; rows -> brow, cols -> bcol
// 128x128 tile, 4 waves (2x2), 4x4 frags of MX-fp8 16x16x128 MFMA, BK=128,
// 4 K-iters. LDS tiles are XOR-swizzled: logical 16B chunk c of row r stored
// at physical chunk c ^ (r&7) (swizzle applied to the GLOBAL address so the
// global_load_lds LDS dest stays lane-contiguous).
__global__ __launch_bounds__(256) void expsum_kernel(
    const uint8_t* __restrict__ h1, const uint8_t* __restrict__ h2,
    float* __restrict__ r1, float* __restrict__ r2,
    float* __restrict__ brow, float* __restrict__ bcol) {
  const int z = blockIdx.z;
  const int i0 = blockIdx.x * 128;
  const int j0 = blockIdx.y * 128;
  if (z != 2 && j0 < i0) return;  // symmetric: lower triangle folded into upper
  const bool diag = (z != 2) && (i0 == j0);

  __shared__ __align__(16) uint8_t As[128 * 128];
  __shared__ __align__(16) uint8_t Bs[128 * 128];
  __shared__ float lds_row[128];
  __shared__ float lds_col[128];

  const uint8_t* Ag = (z == 1) ? h2 : h1;
  const uint8_t* Bg = (z == 0) ? h1 : h2;

  const int t = threadIdx.x;
  const int lane = t & 63;
  const int wave = t >> 6;
  const int wm = wave >> 1;    // row half of tile
  const int wn = wave & 1;     // col half of tile
  const int l16 = lane & 15;
  const int kq = lane >> 4;    // 0..3

  // Staging: one round covers 32 rows (256 thr x 16B = 4KB). Thread t:
  // local row lr = t>>3 (+32 per round), physical chunk p = t&7,
  // logical chunk c = p ^ (row&7); row&7 == lr&7 since rounds step by 32.
  const int lr = t >> 3;
  const int c16 = ((t & 7) ^ (lr & 7)) * 16;
  const size_t ga = (size_t)(i0 + lr) * DIM + c16;
  const size_t gb = (size_t)(j0 + lr) * DIM + c16;
  uint8_t* AsB = As;
  uint8_t* BsB = Bs;
  const int ldst = t * 16;

  f32x4 acc[4][4];
#pragma unroll
  for (int a = 0; a < 4; a++)
#pragma unroll
    for (int b = 0; b < 4; b++)
#pragma unroll
      for (int r = 0; r < 4; r++) acc[a][b][r] = 0.0f;

  for (int kb = 0; kb < 4; kb++) {
    const int k0 = kb * 128;
#pragma unroll
    for (int r4 = 0; r4 < 4; r4++) {
      gload_lds16(Ag + ga + (size_t)r4 * 32 * DIM + k0, AsB + r4 * 4096 + ldst);
      gload_lds16(Bg + gb + (size_t)r4 * 32 * DIM + k0, BsB + r4 * 4096 + ldst);
    }
    __syncthreads();

    Frag8 af[4], bf[4];
#pragma unroll
    for (int f = 0; f < 4; f++) {
      const int rowA = wm * 64 + f * 16 + l16;
      const int sA = rowA & 7;
      af[f].s.lo = *(const i32x4*)(As + rowA * 128 + (((2 * kq) ^ sA) * 16));
      af[f].s.hi = *(const i32x4*)(As + rowA * 128 + (((2 * kq + 1) ^ sA) * 16));
      const int rowB = wn * 64 + f * 16 + l16;
      const int sB = rowB & 7;
      bf[f].s.lo = *(const i32x4*)(Bs + rowB * 128 + (((2 * kq) ^ sB) * 16));
      bf[f].s.hi = *(const i32x4*)(Bs + rowB * 128 + (((2 * kq + 1) ^ sB) * 16));
    }
#pragma unroll
    for (int fm = 0; fm < 4; fm++)
#pragma unroll
      for (int fn = 0; fn < 4; fn++)
        acc[fm][fn] = __builtin_amdgcn_mfma_scale_f32_16x16x128_f8f6f4(
            af[fm].v8, bf[fn].v8, acc[fm][fn],
            0, 0,                    // fmt A = fp8(e4m3), fmt B = fp8(e4m3)
            0, 0x7F7F7F7F,           // scale A: e8m0 127 -> 1.0
            0, 0x7F7F7F7F);          // scale B: 1.0
    __syncthreads();
  }

  // Epilogue: e = exp(s/tau); C/D layout: col = lane&15, row = kq*4 + reg.
  float rowp[4][4];
  float colp[4];
#pragma unroll
  for (int fm = 0; fm < 4; fm++)
#pragma unroll
    for (int r = 0; r < 4; r++) rowp[fm][r] = 0.0f;
#pragma unroll
  for (int fn = 0; fn < 4; fn++) colp[fn] = 0.0f;

#pragma unroll
  for (int fm = 0; fm < 4; fm++)
#pragma unroll
    for (int fn = 0; fn < 4; fn++)
#pragma unroll
      for (int r = 0; r < 4; r++) {
        const float e = __expf(acc[fm][fn][r] * INV_TAU);
        rowp[fm][r] += e;
        colp[fn] += e;
      }

  if (t < 128) lds_row[t] = 0.0f; else lds_col[t - 128] = 0.0f;
  __syncthreads();

#pragma unroll
  for (int fm = 0; fm < 4; fm++) {
#pragma unroll
    for (int r = 0; r < 4; r++) {
      float v = rowp[fm][r];
      v += __shfl_xor(v, 1);
      v += __shfl_xor(v, 2);
      v += __shfl_xor(v, 4);
      v += __shfl_xor(v, 8);
      if (l16 == 0) atomicAdd(&lds_row[wm * 64 + fm * 16 + kq * 4 + r], v);
    }
  }
#pragma unroll
  for (int fn = 0; fn < 4; fn++) {
    float v = colp[fn];
    v += __shfl_xor(v, 16);
    v += __shfl_xor(v, 32);
    if (kq == 0) atomicAdd(&lds_col[wn * 64 + fn * 16 + l16], v);
  }
  __syncthreads();

  if (z == 2) {
    if (t < 128) atomicAdd(&brow[i0 + t], lds_row[t]);
    else         atomicAdd(&bcol[j0 + (t - 128)], lds_col[t - 128]);
  } else {
    float* r = (z == 0) ? r1 : r2;
    if (t < 128) atomicAdd(&r[i0 + t], lds_row[t]);
    else if (!diag) atomicAdd(&r[j0 + (t - 128)], lds_col[t - 128]);
  }
}

__global__ __launch_bounds__(256) void finalize_kernel(
    const float* __restrict__ r1, const float* __restrict__ r2,
    const float* __restrict__ brow, const float* __restrict__ bcol,
    const float* __restrict__ dvec, float* __restrict__ out) {
  const int i = blockIdx.x * 256 + threadIdx.x;
  const float den1 = r1[i] + brow[i] - EXP5;
  const float den2 = r2[i] + bcol[i] - EXP5;
  float v = 0.5f * (logf(den1) + logf(den2)) - INV_TAU * dvec[i];
  for (int m = 32; m; m >>= 1) v += __shfl_xor(v, m);
  __shared__ float red[4];
  const int wave = threadIdx.x >> 6;
  if ((threadIdx.x & 63) == 0) red[wave] = v;
  __syncthreads();
  if (threadIdx.x == 0) atomicAdd(out, red[0] + red[1] + red[2] + red[3]);
}

extern "C" void kernel_launch(void* const* d_in, const int* in_sizes, int n_in,
                              void* d_out, int out_size, void* d_ws, size_t ws_size,
                              hipStream_t stream) {
  const float* z1 = (const float*)d_in[0];
  const float* z2 = (const float*)d_in[1];
  float* out = (float*)d_out;

  char* ws = (char*)d_ws;
  uint8_t* h1 = (uint8_t*)ws;                           // 4 MiB fp8
  uint8_t* h2 = (uint8_t*)(ws + (4 << 20));             // 4 MiB fp8
  float* r1   = (float*)(ws + (8 << 20));
  float* r2   = r1 + N_ROWS;
  float* brow = r2 + N_ROWS;
  float* bcol = brow + N_ROWS;
  float* dvec = bcol + N_ROWS;

  normalize_kernel<<<N_ROWS, 256, 0, stream>>>(z1, z2, h1, h2, dvec,
                                               r1, r2, brow, bcol, out);
  expsum_kernel<<<dim3(64, 64, 3), 256, 0, stream>>>(h1, h2, r1, r2, brow, bcol);
  finalize_kernel<<<N_ROWS / 256, 256, 0, stream>>>(r1, r2, brow, bcol, dvec, out);
}

// Round 4
// 286.653 us; speedup vs baseline: 1.2470x; 1.2470x over previous
//
#include <hip/hip_runtime.h>
#include <hip/hip_bf16.h>
#include <math.h>
#include <stdint.h>

#define N_ROWS 8192
#define DIM 512
#define INV_TAU 5.0f
#define EXP5 148.41315910257660342f   // exp(1/tau) = exp(5)
#define BM 128
#define BN 256

typedef float f32x4 __attribute__((ext_vector_type(4)));
typedef __bf16 bf16x8 __attribute__((ext_vector_type(8)));

__device__ __forceinline__ void gload_lds16(const void* g, void* l) {
  __builtin_amdgcn_global_load_lds(
      (__attribute__((address_space(1))) void*)(void*)g,
      (__attribute__((address_space(3))) void*)l,
      16, 0, 0);
}

// One block per row: L2 norms of z1,z2 row, fp32 diag dot, bf16 h1,h2.
// Also zeroes the accumulator arrays and out (replaces memsets).
__global__ __launch_bounds__(256) void normalize_kernel(
    const float* __restrict__ z1, const float* __restrict__ z2,
    __hip_bfloat16* __restrict__ h1, __hip_bfloat16* __restrict__ h2,
    float* __restrict__ dvec,
    float* __restrict__ r1, float* __restrict__ r2,
    float* __restrict__ brow, float* __restrict__ bcol,
    float* __restrict__ out) {
  const int row = blockIdx.x;
  const int t = threadIdx.x;
  const float2 a = ((const float2*)(z1 + (size_t)row * DIM))[t];
  const float2 b = ((const float2*)(z2 + (size_t)row * DIM))[t];
  float s1 = a.x * a.x + a.y * a.y;
  float s2 = b.x * b.x + b.y * b.y;
  float s3 = a.x * b.x + a.y * b.y;
  for (int m = 32; m; m >>= 1) {
    s1 += __shfl_xor(s1, m);
    s2 += __shfl_xor(s2, m);
    s3 += __shfl_xor(s3, m);
  }
  __shared__ float red[3][4];
  const int wave = t >> 6;
  if ((t & 63) == 0) { red[0][wave] = s1; red[1][wave] = s2; red[2][wave] = s3; }
  __syncthreads();
  const float S1 = red[0][0] + red[0][1] + red[0][2] + red[0][3];
  const float S2 = red[1][0] + red[1][1] + red[1][2] + red[1][3];
  const float S3 = red[2][0] + red[2][1] + red[2][2] + red[2][3];
  const float inv1 = 1.0f / fmaxf(sqrtf(S1), 1e-12f);
  const float inv2 = 1.0f / fmaxf(sqrtf(S2), 1e-12f);
  __hip_bfloat162 v1, v2;
  v1.x = __float2bfloat16(a.x * inv1); v1.y = __float2bfloat16(a.y * inv1);
  v2.x = __float2bfloat16(b.x * inv2); v2.y = __float2bfloat16(b.y * inv2);
  ((__hip_bfloat162*)(h1 + (size_t)row * DIM))[t] = v1;
  ((__hip_bfloat162*)(h2 + (size_t)row * DIM))[t] = v2;
  if (t == 0) {
    dvec[row] = S3 * inv1 * inv2;
    r1[row] = 0.0f; r2[row] = 0.0f; brow[row] = 0.0f; bcol[row] = 0.0f;
    if (row == 0) out[0] = 0.0f;
  }
}

// grid (64, 32, 3); block tile BM x BN = 128 x 256; 4 waves in 2x2, each wave
// 64x128 via 4x8 frags of 16x16x32 bf16 MFMA (43.7 MFMA-FLOP per DS byte vs
// 32 for the 4x4 layout). Symmetric planes (z=0: h1 h1^T -> r1, z=1: h2 h2^T
// -> r2): blocks fully below the diagonal exit; the 2 diagonal-straddling
// blocks per bj predicate per element (rows: gi<=gj, cols: gi<gj) so each
// unordered pair is counted exactly once; strictly-upper blocks add rows and
// cols unconditionally (cols stand in for the mirrored block's rows).
// z=2 (h1 h2^T): full grid, rows -> brow, cols -> bcol.
__global__ __launch_bounds__(256, 2) void expsum_kernel(
    const __hip_bfloat16* __restrict__ h1, const __hip_bfloat16* __restrict__ h2,
    float* __restrict__ r1, float* __restrict__ r2,
    float* __restrict__ brow, float* __restrict__ bcol) {
  const int z = blockIdx.z;
  const int bi = blockIdx.x;
  const int bj = blockIdx.y;
  if (z != 2 && bi >= 2 * bj + 2) return;          // fully below diagonal
  const bool needPred = (z != 2) && (bi >= 2 * bj); // straddles diagonal
  const int i0 = bi * BM;
  const int j0 = bj * BN;

  __shared__ __align__(16) __hip_bfloat16 As[BM * 32];
  __shared__ __align__(16) __hip_bfloat16 Bs[BN * 32];
  __shared__ float lds_row[BM];
  __shared__ float lds_col[BN];

  const __hip_bfloat16* Ag = (z == 1) ? h2 : h1;
  const __hip_bfloat16* Bg = (z == 0) ? h1 : h2;

  const int t = threadIdx.x;
  const int wave = t >> 6;
  const int lane = t & 63;
  const int wm = wave >> 1;    // 0..1: 64-row half
  const int wn = wave & 1;     // 0..1: 128-col half
  const int l16 = lane & 15;
  const int kq = lane >> 4;    // 0..3

  // staging: LDS row-major [rows][32] bf16 (64 B/row per kb). Each round of
  // 256 threads covers 64 rows: row = r*64 + t>>2, 16B chunk t&3.
  const int srow = t >> 2;
  const int skoff = (t & 3) * 8;
  const size_t ab = (size_t)(i0 + srow) * DIM + skoff;
  const size_t bb = (size_t)(j0 + srow) * DIM + skoff;
  char* AsB = (char*)As;
  char* BsB = (char*)Bs;
  const int ldst = t * 16;

  f32x4 acc[4][8];
#pragma unroll
  for (int a = 0; a < 4; a++)
#pragma unroll
    for (int b = 0; b < 8; b++)
#pragma unroll
      for (int r = 0; r < 4; r++) acc[a][b][r] = 0.0f;

  for (int kb = 0; kb < DIM / 32; kb++) {
    const int k0 = kb * 32;
    gload_lds16(Ag + ab + k0, AsB + ldst);
    gload_lds16(Ag + ab + (size_t)64 * DIM + k0, AsB + 4096 + ldst);
#pragma unroll
    for (int r4 = 0; r4 < 4; r4++)
      gload_lds16(Bg + bb + (size_t)(r4 * 64) * DIM + k0, BsB + r4 * 4096 + ldst);
    __syncthreads();

    bf16x8 afrag[4], bfrag[8];
#pragma unroll
    for (int f = 0; f < 4; f++)
      afrag[f] = *(const bf16x8*)(AsB + ((wm * 64 + f * 16 + l16) * 32 + kq * 8) * 2);
#pragma unroll
    for (int f = 0; f < 8; f++)
      bfrag[f] = *(const bf16x8*)(BsB + ((wn * 128 + f * 16 + l16) * 32 + kq * 8) * 2);
#pragma unroll
    for (int fm = 0; fm < 4; fm++)
#pragma unroll
      for (int fn = 0; fn < 8; fn++)
        acc[fm][fn] = __builtin_amdgcn_mfma_f32_16x16x32_bf16(
            afrag[fm], bfrag[fn], acc[fm][fn], 0, 0, 0);
    __syncthreads();
  }

  // Epilogue. C/D layout: col = lane&15, row = kq*4 + reg.
  float rowp[4][4];
  float colp[8];
#pragma unroll
  for (int fm = 0; fm < 4; fm++)
#pragma unroll
    for (int r = 0; r < 4; r++) rowp[fm][r] = 0.0f;
#pragma unroll
  for (int fn = 0; fn < 8; fn++) colp[fn] = 0.0f;

  if (!needPred) {
#pragma unroll
    for (int fm = 0; fm < 4; fm++)
#pragma unroll
      for (int fn = 0; fn < 8; fn++)
#pragma unroll
        for (int r = 0; r < 4; r++) {
          const float e = __expf(acc[fm][fn][r] * INV_TAU);
          rowp[fm][r] += e;
          colp[fn] += e;
        }
  } else {
    const int gi_b = i0 + wm * 64 + kq * 4;   // + fm*16 + r
    const int gj_b = j0 + wn * 128 + l16;     // + fn*16
#pragma unroll
    for (int fm = 0; fm < 4; fm++)
#pragma unroll
      for (int fn = 0; fn < 8; fn++)
#pragma unroll
        for (int r = 0; r < 4; r++) {
          const int gi = gi_b + fm * 16 + r;
          const int gj = gj_b + fn * 16;
          const float e = __expf(acc[fm][fn][r] * INV_TAU);
          rowp[fm][r] += (gi <= gj) ? e : 0.0f;
          colp[fn] += (gi < gj) ? e : 0.0f;
        }
  }

  if (t < BM) lds_row[t] = 0.0f;
  lds_col[t] = 0.0f;
  __syncthreads();

  // Row sums: reduce across the 16 lanes (cols) sharing kq.
#pragma unroll
  for (int fm = 0; fm < 4; fm++) {
#pragma unroll
    for (int r = 0; r < 4; r++) {
      float v = rowp[fm][r];
      v += __shfl_xor(v, 1);
      v += __shfl_xor(v, 2);
      v += __shfl_xor(v, 4);
      v += __shfl_xor(v, 8);
      if (l16 == 0) atomicAdd(&lds_row[wm * 64 + fm * 16 + kq * 4 + r], v);
    }
  }
  // Col sums: reduce across the 4 kq groups (rows).
#pragma unroll
  for (int fn = 0; fn < 8; fn++) {
    float v = colp[fn];
    v += __shfl_xor(v, 16);
    v += __shfl_xor(v, 32);
    if (kq == 0) atomicAdd(&lds_col[wn * 128 + fn * 16 + l16], v);
  }
  __syncthreads();

  if (z == 2) {
    if (t < BM) atomicAdd(&brow[i0 + t], lds_row[t]);
    atomicAdd(&bcol[j0 + t], lds_col[t]);
  } else {
    float* r = (z == 0) ? r1 : r2;
    if (t < BM) atomicAdd(&r[i0 + t], lds_row[t]);
    atomicAdd(&r[j0 + t], lds_col[t]);
  }
}

__global__ __launch_bounds__(256) void finalize_kernel(
    const float* __restrict__ r1, const float* __restrict__ r2,
    const float* __restrict__ brow, const float* __restrict__ bcol,
    const float* __restrict__ dvec, float* __restrict__ out) {
  const int i = blockIdx.x * 256 + threadIdx.x;
  const float den1 = r1[i] + brow[i] - EXP5;
  const float den2 = r2[i] + bcol[i] - EXP5;
  float v = 0.5f * (logf(den1) + logf(den2)) - INV_TAU * dvec[i];
  for (int m = 32; m; m >>= 1) v += __shfl_xor(v, m);
  __shared__ float red[4];
  const int wave = threadIdx.x >> 6;
  if ((threadIdx.x & 63) == 0) red[wave] = v;
  __syncthreads();
  if (threadIdx.x == 0) atomicAdd(out, red[0] + red[1] + red[2] + red[3]);
}

extern "C" void kernel_launch(void* const* d_in, const int* in_sizes, int n_in,
                              void* d_out, int out_size, void* d_ws, size_t ws_size,
                              hipStream_t stream) {
  const float* z1 = (const float*)d_in[0];
  const float* z2 = (const float*)d_in[1];
  float* out = (float*)d_out;

  char* ws = (char*)d_ws;
  __hip_bfloat16* h1 = (__hip_bfloat16*)ws;                   // 8 MiB
  __hip_bfloat16* h2 = (__hip_bfloat16*)(ws + 8388608);       // 8 MiB
  float* r1   = (float*)(ws + 16777216);
  float* r2   = r1 + N_ROWS;
  float* brow = r2 + N_ROWS;
  float* bcol = brow + N_ROWS;
  float* dvec = bcol + N_ROWS;

  normalize_kernel<<<N_ROWS, 256, 0, stream>>>(z1, z2, h1, h2, dvec,
                                               r1, r2, brow, bcol, out);
  expsum_kernel<<<dim3(64, 32, 3), 256, 0, stream>>>(h1, h2, r1, r2, brow, bcol);
  finalize_kernel<<<N_ROWS / 256, 256, 0, stream>>>(r1, r2, brow, bcol, dvec, out);
}